// Round 4
// baseline (159.496 us; speedup 1.0000x reference)
//
#include <hip/hip_runtime.h>
#include <cstdint>
#include <cstddef>

typedef short s16x8 __attribute__((ext_vector_type(8)));
typedef float f32x16 __attribute__((ext_vector_type(16)));

#define WS_S     0
#define WS_ZERO  16384
#define WS_XQ    32768
#define XQ_BYTES (8 * 64 * 64 * 64 * 16)          // 33554432
#define WS_WQ    (WS_XQ + XQ_BYTES)               // 33587200
#define WQ_BYTES (8 * 32 * 9 * 2 * 64 * 8 * 2)    // 4718592
#define WS_NEEDED ((size_t)WS_WQ + (size_t)WQ_BYTES)

__device__ __forceinline__ short f2bf(float f) {
  unsigned u = __builtin_bit_cast(unsigned, f);
  unsigned r = (u + 0x7fffu + ((u >> 16) & 1u)) >> 16;  // RNE
  return (short)r;
}

__device__ __forceinline__ void gload_lds16(const void* g, void* l) {
  __builtin_amdgcn_global_load_lds(
      (const __attribute__((address_space(1))) void*)g,
      (__attribute__((address_space(3))) void*)l, 16, 0, 0);
}

// ---- s = style @ mod_w^T + mod_b ; one wave per (b,c). Also zeroes zerobuf.
__global__ void k_style(const float* __restrict__ style,
                        const float* __restrict__ mod_w,
                        const float* __restrict__ mod_b,
                        float* __restrict__ s_out,
                        float* __restrict__ zb) {
  if (blockIdx.x == 0) zb[threadIdx.x] = 0.0f;  // 256 floats = 1 KB zero page
  int wave = threadIdx.x >> 6, lane = threadIdx.x & 63;
  int wid = blockIdx.x * 4 + wave;   // 0..4095
  int b = wid >> 9, c = wid & 511;
  const float4* st = (const float4*)(style + b * 512);
  const float4* mw = (const float4*)(mod_w + c * 512);
  float4 a0 = st[lane * 2], a1 = st[lane * 2 + 1];
  float4 b0 = mw[lane * 2], b1 = mw[lane * 2 + 1];
  float sum = a0.x * b0.x + a0.y * b0.y + a0.z * b0.z + a0.w * b0.w +
              a1.x * b1.x + a1.y * b1.y + a1.z * b1.z + a1.w * b1.w;
  #pragma unroll
  for (int off = 32; off; off >>= 1) sum += __shfl_down(sum, off);
  if (lane == 0) s_out[b * 512 + c] = sum + mod_b[c];
}

// ---- xq[b][h][cgrp][w][8] = bf16(x[b][cgrp*8+j][h][w] * s[b][cgrp*8+j])
__global__ void k_xq(const float* __restrict__ x, const float* __restrict__ s,
                     char* __restrict__ xq) {
  int t = blockIdx.x * 256 + threadIdx.x;        // 2,097,152 total
  int w = t & 63, cg = (t >> 6) & 63, h = (t >> 12) & 63, b = t >> 18;
  const float* xp = x + (((b * 512 + cg * 8) * 64 + h) * 64 + w);
  const float* sp = s + b * 512 + cg * 8;
  s16x8 v;
  #pragma unroll
  for (int j = 0; j < 8; ++j) v[j] = f2bf(xp[j * 4096] * sp[j]);
  *(s16x8*)(xq + (size_t)t * 16) = v;
}

// ---- wq[nb8][chunk][tap][kg][n64][8k] = bf16(weight[nb*64+n][chunk*16+kg*8+k][tap])
__global__ void k_wq(const float* __restrict__ wt, char* __restrict__ wq) {
  int tap = blockIdx.x, ch = blockIdx.y, nb = blockIdx.z;
  int kg = threadIdx.x >> 6, n = threadIdx.x & 63;   // 128 threads
  const float* wp = wt + ((size_t)(nb * 64 + n) * 512 + ch * 16 + kg * 8) * 9 + tap;
  s16x8 v;
  #pragma unroll
  for (int j = 0; j < 8; ++j) v[j] = f2bf(wp[j * 9]);
  size_t idx = ((size_t)(nb * 32 + ch) * 9 + tap) * 128 + kg * 64 + n;  // 16B units
  *(s16x8*)(wq + idx * 16) = v;
}

// ---- conv: block = 64 couts (nb) x 512 pixels (8 rows of one image)
// 4 waves (one per 2-row pixel slice), wave tile 64 couts x 128 px.
// LDS/block = 2*(18432 + 21120) = 79104 B -> 2 independent blocks/CU, so one
// block's chunk barrier is covered by the other block's compute.
__global__ __launch_bounds__(256, 2) void k_conv(
    const char* __restrict__ xq, const char* __restrict__ wq,
    const char* __restrict__ zerob, float* __restrict__ out) {
  extern __shared__ char smem[];
  // layout: wt[2][18432] then xs[2][21120]   total 79104 B
  char* wt_base = smem;
  char* xs_base = smem + 36864;

  const int tid = threadIdx.x;
  const int lane = tid & 63, wave = tid >> 6;   // wave = pixel slice wp (0..3)
  const int l5 = lane >> 5, l31 = lane & 31;
  const int mb = blockIdx.x, nb = blockIdx.y;
  const int b = mb >> 3;               // 8 m-blocks (of 8 rows) per image
  const int row0 = (mb & 7) << 3;      // first of the 8 output rows

  // zero halo columns (col 0 and 65 of each [row j][kg] plane) in BOTH buffers
  if (tid < 80) {
    int dbuf = tid / 40, q = tid % 40;
    int j = q >> 2, kg = (q >> 1) & 1, side = q & 1;
    s16x8 z = {0, 0, 0, 0, 0, 0, 0, 0};
    *(s16x8*)(xs_base + dbuf * 21120 + ((j * 2 + kg) * 66 + side * 65) * 16) = z;
  }

  f32x16 acc[2][4];
  #pragma unroll
  for (int i = 0; i < 2; ++i)
    #pragma unroll
    for (int j = 0; j < 4; ++j)
      #pragma unroll
      for (int e = 0; e < 16; ++e) acc[i][j][e] = 0.0f;

  // staging source bases (per-lane)
  const char* wq_base = wq + (size_t)nb * (32 * 18432) + lane * 16;
  const char* xq_base = xq + (size_t)b * 4194304 + lane * 16;

  const int a_off = l5 * 1024 + l31 * 16;       // within wt chunk (kg, n)
  const int b_off = l5 * 1056 + l31 * 16;       // within xs chunk (kg, col)
  const int xs_woff = wave * 4224;              // wave's 2-row pixel slice

  // ---- stage chunk `ch` into buffer `buf`: 38 x 1KB segs (18 wt + 20 xs)
  #define STAGE(buf, ch)                                                      \
    _Pragma("unroll")                                                         \
    for (int i = 0; i < 10; ++i) {                                            \
      int seg = wave * 10 + i;            /* wave-uniform */                  \
      if (seg < 18) {                                                         \
        gload_lds16(wq_base + (size_t)(ch) * 18432 + seg * 1024,              \
                    wt_base + (buf) * 18432 + seg * 1024);                    \
      } else if (seg < 38) {                                                  \
        int q = seg - 18, j = q >> 1, kg = q & 1;                             \
        int h = row0 - 1 + j;                                                 \
        const char* src = (h >= 0 && h < 64)                                  \
            ? xq_base + (size_t)(h * 64 + (ch) * 2 + kg) * 1024               \
            : zerob + lane * 16;                                              \
        gload_lds16(src, xs_base + (buf) * 21120 + ((j * 2 + kg) * 66 + 1) * 16); \
      }                                                                       \
    }

  STAGE(0, 0);
  __syncthreads();   // drains vmcnt + the halo ds_writes

  for (int ch = 0; ch < 32; ++ch) {
    const int cur = ch & 1;
    if (ch < 31) STAGE(cur ^ 1, ch + 1);

    const char* wt = wt_base + cur * 18432;
    const char* xs_w = xs_base + cur * 21120 + xs_woff;

    #pragma unroll
    for (int kw = 0; kw < 3; ++kw) {
      // B-fragment cache: 4 input rows x 2 col-halves, reused across kh
      s16x8 bC[4][2];
      #pragma unroll
      for (int r4 = 0; r4 < 4; ++r4)
        #pragma unroll
        for (int chh = 0; chh < 2; ++chh)
          bC[r4][chh] = *(const s16x8*)(xs_w + (r4 * 132 + chh * 32 + kw) * 16 + b_off);
      #pragma unroll
      for (int kh = 0; kh < 3; ++kh) {
        const int tap = kh * 3 + kw;
        s16x8 afr[2];
        #pragma unroll
        for (int ct = 0; ct < 2; ++ct)
          afr[ct] = *(const s16x8*)(wt + tap * 2048 + ct * 512 + a_off);
        #pragma unroll
        for (int ct = 0; ct < 2; ++ct)
          #pragma unroll
          for (int pt = 0; pt < 4; ++pt)
            acc[ct][pt] = __builtin_amdgcn_mfma_f32_32x32x16_bf16(
                afr[ct], bC[(pt >> 1) + kh][pt & 1], acc[ct][pt], 0, 0, 0);
      }
    }
    __syncthreads();   // implicit vmcnt(0): next buffer staged; reads of cur done
  }

  // epilogue: D row = cout, col = pixel (lanes 0..31 contiguous w -> coalesced)
  #pragma unroll
  for (int ct = 0; ct < 2; ++ct) {
    #pragma unroll
    for (int pt = 0; pt < 4; ++pt) {
      int h = row0 + wave * 2 + (pt >> 1);
      int w = (pt & 1) * 32 + l31;
      int cb = nb * 64 + ct * 32 + 4 * l5;
      #pragma unroll
      for (int rg = 0; rg < 16; ++rg) {
        int cout = cb + (rg & 3) + 8 * (rg >> 2);
        out[((size_t)(b * 512 + cout) * 4096) + h * 64 + w] = acc[ct][pt][rg];
      }
    }
  }
  #undef STAGE
}

// ---- emergency fallback (tiny ws): fp32 direct conv, s recomputed per block
__global__ void k_naive(const float* __restrict__ x, const float* __restrict__ style,
                        const float* __restrict__ wt, const float* __restrict__ mw,
                        const float* __restrict__ mb_, float* __restrict__ out) {
  __shared__ float s_sh[512];
  int h = blockIdx.x, co = blockIdx.y, b = blockIdx.z, w = threadIdx.x;
  for (int c = w; c < 512; c += 64) {
    float a = mb_[c];
    for (int k = 0; k < 512; ++k) a += style[b * 512 + k] * mw[c * 512 + k];
    s_sh[c] = a;
  }
  __syncthreads();
  float acc = 0.0f;
  for (int c = 0; c < 512; ++c) {
    float sc = s_sh[c];
    const float* wp = wt + ((size_t)co * 512 + c) * 9;
    for (int kh = 0; kh < 3; ++kh) {
      int hy = h + kh - 1;
      if (hy < 0 || hy >= 64) continue;
      for (int kw = 0; kw < 3; ++kw) {
        int wx = w + kw - 1;
        if (wx < 0 || wx >= 64) continue;
        acc += wp[kh * 3 + kw] * x[((size_t)(b * 512 + c) * 64 + hy) * 64 + wx] * sc;
      }
    }
  }
  out[((size_t)(b * 512 + co) * 64 + h) * 64 + w] = acc;
}

extern "C" void kernel_launch(void* const* d_in, const int* in_sizes, int n_in,
                              void* d_out, int out_size, void* d_ws, size_t ws_size,
                              hipStream_t stream) {
  const float* x      = (const float*)d_in[0];
  const float* style  = (const float*)d_in[1];
  const float* weight = (const float*)d_in[2];
  const float* mod_w  = (const float*)d_in[3];
  const float* mod_b  = (const float*)d_in[4];
  float* out = (float*)d_out;
  char* ws = (char*)d_ws;

  if (ws_size >= WS_NEEDED) {
    float* s  = (float*)(ws + WS_S);
    float* zb = (float*)(ws + WS_ZERO);
    char* xq  = ws + WS_XQ;
    char* wq  = ws + WS_WQ;
    k_style<<<1024, 256, 0, stream>>>(style, mod_w, mod_b, s, zb);
    k_xq<<<8192, 256, 0, stream>>>(x, s, xq);
    k_wq<<<dim3(9, 32, 8), 128, 0, stream>>>(weight, wq);
    k_conv<<<dim3(64, 8), 256, 79104, stream>>>(xq, wq, (const char*)zb, out);
  } else {
    k_naive<<<dim3(64, 512, 8), 64, 0, stream>>>(x, style, weight, mod_w, mod_b, out);
  }
}

// Round 5
// 155.243 us; speedup vs baseline: 1.0274x; 1.0274x over previous
//
#include <hip/hip_runtime.h>
#include <cstdint>
#include <cstddef>

typedef short s16x8 __attribute__((ext_vector_type(8)));
typedef float f32x16 __attribute__((ext_vector_type(16)));

#define WS_S     0
#define WS_ZERO  16384
#define WS_XQ    32768
#define XQ_BYTES (8 * 64 * 64 * 64 * 16)          // 33554432
#define WS_WQ    (WS_XQ + XQ_BYTES)               // 33587200
#define WQ_BYTES (4 * 32 * 9 * 2 * 128 * 8 * 2)   // 4718592
#define WS_NEEDED ((size_t)WS_WQ + (size_t)WQ_BYTES)

__device__ __forceinline__ short f2bf(float f) {
  unsigned u = __builtin_bit_cast(unsigned, f);
  unsigned r = (u + 0x7fffu + ((u >> 16) & 1u)) >> 16;  // RNE
  return (short)r;
}

__device__ __forceinline__ void gload_lds16(const void* g, void* l) {
  __builtin_amdgcn_global_load_lds(
      (const __attribute__((address_space(1))) void*)g,
      (__attribute__((address_space(3))) void*)l, 16, 0, 0);
}

// ---- s = style @ mod_w^T + mod_b ; one wave per (b,c). Also zeroes zerobuf.
__global__ void k_style(const float* __restrict__ style,
                        const float* __restrict__ mod_w,
                        const float* __restrict__ mod_b,
                        float* __restrict__ s_out,
                        float* __restrict__ zb) {
  if (blockIdx.x == 0) zb[threadIdx.x] = 0.0f;  // 256 floats = 1 KB zero page
  int wave = threadIdx.x >> 6, lane = threadIdx.x & 63;
  int wid = blockIdx.x * 4 + wave;   // 0..4095
  int b = wid >> 9, c = wid & 511;
  const float4* st = (const float4*)(style + b * 512);
  const float4* mw = (const float4*)(mod_w + c * 512);
  float4 a0 = st[lane * 2], a1 = st[lane * 2 + 1];
  float4 b0 = mw[lane * 2], b1 = mw[lane * 2 + 1];
  float sum = a0.x * b0.x + a0.y * b0.y + a0.z * b0.z + a0.w * b0.w +
              a1.x * b1.x + a1.y * b1.y + a1.z * b1.z + a1.w * b1.w;
  #pragma unroll
  for (int off = 32; off; off >>= 1) sum += __shfl_down(sum, off);
  if (lane == 0) s_out[b * 512 + c] = sum + mod_b[c];
}

// ---- xq[b][h][cgrp][w][8] = bf16(x[b][cgrp*8+j][h][w] * s[b][cgrp*8+j])
__global__ void k_xq(const float* __restrict__ x, const float* __restrict__ s,
                     char* __restrict__ xq) {
  int t = blockIdx.x * 256 + threadIdx.x;        // 2,097,152 total
  int w = t & 63, cg = (t >> 6) & 63, h = (t >> 12) & 63, b = t >> 18;
  const float* xp = x + (((b * 512 + cg * 8) * 64 + h) * 64 + w);
  const float* sp = s + b * 512 + cg * 8;
  s16x8 v;
  #pragma unroll
  for (int j = 0; j < 8; ++j) v[j] = f2bf(xp[j * 4096] * sp[j]);
  *(s16x8*)(xq + (size_t)t * 16) = v;
}

// ---- wq[nb][chunk][tap][kg][n][8k] = bf16(weight[nb*128+n][chunk*16+kg*8+k][tap])
__global__ void k_wq(const float* __restrict__ wt, char* __restrict__ wq) {
  int tap = blockIdx.x, ch = blockIdx.y, nb = blockIdx.z;
  int kg = threadIdx.x >> 7, n = threadIdx.x & 127;
  const float* wp = wt + ((size_t)(nb * 128 + n) * 512 + ch * 16 + kg * 8) * 9 + tap;
  s16x8 v;
  #pragma unroll
  for (int j = 0; j < 8; ++j) v[j] = f2bf(wp[j * 9]);
  size_t idx = ((size_t)(nb * 32 + ch) * 9 + tap) * 256 + kg * 128 + n;  // 16B units
  *(s16x8*)(wq + idx * 16) = v;
}

// ---- conv: block = 128 couts (nb) x 512 pixels (8 rows of one image)
// 8 waves (2 cout-halves x 4 pixel-slices), wave tile 64 couts x 128 px.
// Chunk body is software-pipelined at fragment level: 9 clusters of 8 MFMA;
// cluster i prefetches cluster i+1's A/B fragments into register dbufs so the
// LDS pipe runs underneath the MFMA clusters instead of in lockstep bursts.
__global__ __launch_bounds__(512, 2) void k_conv(
    const char* __restrict__ xq, const char* __restrict__ wq,
    const char* __restrict__ zerob, float* __restrict__ out) {
  extern __shared__ char smem[];
  // layout: wt[2][36864] then xs[2][21120]   total 115968 B
  char* wt_base = smem;
  char* xs_base = smem + 73728;

  const int tid = threadIdx.x;
  const int lane = tid & 63, wave = tid >> 6;
  const int l5 = lane >> 5, l31 = lane & 31;
  const int wc = wave >> 2;            // cout half (0,1)
  const int wp = wave & 3;             // pixel slice (2 rows each)
  const int mb = blockIdx.x, nb = blockIdx.y;
  const int b = mb >> 3;               // 8 m-blocks (of 8 rows) per image
  const int row0 = (mb & 7) << 3;      // first of the 8 output rows

  // zero halo columns (col 0 and 65 of each [row j][kg] plane) in BOTH buffers
  if (tid < 80) {
    int dbuf = tid / 40, q = tid % 40;
    int j = q >> 2, kg = (q >> 1) & 1, side = q & 1;
    s16x8 z = {0, 0, 0, 0, 0, 0, 0, 0};
    *(s16x8*)(xs_base + dbuf * 21120 + ((j * 2 + kg) * 66 + side * 65) * 16) = z;
  }

  f32x16 acc[2][4];
  #pragma unroll
  for (int i = 0; i < 2; ++i)
    #pragma unroll
    for (int j = 0; j < 4; ++j)
      #pragma unroll
      for (int e = 0; e < 16; ++e) acc[i][j][e] = 0.0f;

  // staging source bases (per-lane)
  const char* wq_base = wq + (size_t)nb * (32 * 36864) + lane * 16;
  const char* xq_base = xq + (size_t)b * 4194304 + lane * 16;

  const int a_off = (wc * 2) * 512 + l5 * 2048 + l31 * 16;  // wt: this wave's cout half
  const int b_off = l5 * 1056 + l31 * 16;                   // xs: (kg, col) within plane
  const int xs_woff = wp * 4224;                            // wave's 2-row pixel slice

  // ---- stage chunk `ch` into buffer `buf`: 56 x 1KB segs, 7 per wave
  #define STAGE(buf, ch)                                                      \
    _Pragma("unroll")                                                         \
    for (int i = 0; i < 7; ++i) {                                             \
      int seg = wave * 7 + i;             /* 0..55, wave-uniform */           \
      if (seg < 36) {                                                         \
        gload_lds16(wq_base + (size_t)(ch) * 36864 + seg * 1024,              \
                    wt_base + (buf) * 36864 + seg * 1024);                    \
      } else {                                                                \
        int q = seg - 36, j = q >> 1, kg = q & 1;                             \
        int h = row0 - 1 + j;                                                 \
        const char* src = (h >= 0 && h < 64)                                  \
            ? xq_base + (size_t)(h * 64 + (ch) * 2 + kg) * 1024               \
            : zerob + lane * 16;                                              \
        gload_lds16(src, xs_base + (buf) * 21120 + ((j * 2 + kg) * 66 + 1) * 16); \
      }                                                                       \
    }

  STAGE(0, 0);
  __syncthreads();   // drains vmcnt + the halo ds_writes

  // fragment register double-buffers
  s16x8 bCb[2][4][2];   // [kw parity][input row r][col half]
  s16x8 afb[2][2];      // [cluster parity][ct]

  #define RD_AFR(dst, tap)                                                    \
    { dst[0] = *(const s16x8*)(wtc + (tap) * 4096 + 0 * 512 + a_off);         \
      dst[1] = *(const s16x8*)(wtc + (tap) * 4096 + 1 * 512 + a_off); }
  #define RD_BC(buf, kwv, r)                                                  \
    { buf[r][0] = *(const s16x8*)(xsw + ((r) * 132 + 0 * 32 + (kwv)) * 16 + b_off); \
      buf[r][1] = *(const s16x8*)(xsw + ((r) * 132 + 1 * 32 + (kwv)) * 16 + b_off); }

  for (int ch = 0; ch < 32; ++ch) {
    const int cur = ch & 1;
    if (ch < 31) STAGE(cur ^ 1, ch + 1);

    const char* wtc = wt_base + cur * 36864;
    const char* xsw = xs_base + cur * 21120 + xs_woff;

    // chunk prologue: fragments for cluster 0 (kw=0, kh=0)
    RD_BC(bCb[0], 0, 0); RD_BC(bCb[0], 0, 1);
    RD_BC(bCb[0], 0, 2); RD_BC(bCb[0], 0, 3);
    RD_AFR(afb[0], 0);

    // 9 clusters: cl = kw*3 + kh, tap = kh*3 + kw
    #pragma unroll
    for (int cl = 0; cl < 9; ++cl) {
      const int kw = cl / 3, kh = cl % 3;
      const int kwp = kw & 1, clp = cl & 1;

      // prefetch next cluster's A fragments
      if (cl < 8) {
        const int nkw = (cl + 1) / 3, nkh = (cl + 1) % 3;
        RD_AFR(afb[clp ^ 1], nkh * 3 + nkw);
      }
      // prefetch next kw's B fragments, spread over kh=1 (rows 0-1) and kh=2 (rows 2-3)
      if (kw < 2 && kh == 1) { RD_BC(bCb[kwp ^ 1], kw + 1, 0); RD_BC(bCb[kwp ^ 1], kw + 1, 1); }
      if (kw < 2 && kh == 2) { RD_BC(bCb[kwp ^ 1], kw + 1, 2); RD_BC(bCb[kwp ^ 1], kw + 1, 3); }

      __builtin_amdgcn_s_setprio(1);
      #pragma unroll
      for (int ct = 0; ct < 2; ++ct)
        #pragma unroll
        for (int pt = 0; pt < 4; ++pt)
          acc[ct][pt] = __builtin_amdgcn_mfma_f32_32x32x16_bf16(
              afb[clp][ct], bCb[kwp][(pt >> 1) + kh][pt & 1], acc[ct][pt], 0, 0, 0);
      __builtin_amdgcn_s_setprio(0);
    }
    __syncthreads();   // implicit vmcnt(0): next buffer staged; reads of cur done
  }

  // epilogue: D row = cout, col = pixel (lanes 0..31 contiguous w -> coalesced)
  #pragma unroll
  for (int ct = 0; ct < 2; ++ct) {
    #pragma unroll
    for (int pt = 0; pt < 4; ++pt) {
      int h = row0 + wp * 2 + (pt >> 1);
      int w = (pt & 1) * 32 + l31;
      int cb = nb * 128 + wc * 64 + ct * 32 + 4 * l5;
      #pragma unroll
      for (int rg = 0; rg < 16; ++rg) {
        int cout = cb + (rg & 3) + 8 * (rg >> 2);
        out[((size_t)(b * 512 + cout) * 4096) + h * 64 + w] = acc[ct][pt][rg];
      }
    }
  }
  #undef STAGE
  #undef RD_AFR
  #undef RD_BC
}

// ---- emergency fallback (tiny ws): fp32 direct conv, s recomputed per block
__global__ void k_naive(const float* __restrict__ x, const float* __restrict__ style,
                        const float* __restrict__ wt, const float* __restrict__ mw,
                        const float* __restrict__ mb_, float* __restrict__ out) {
  __shared__ float s_sh[512];
  int h = blockIdx.x, co = blockIdx.y, b = blockIdx.z, w = threadIdx.x;
  for (int c = w; c < 512; c += 64) {
    float a = mb_[c];
    for (int k = 0; k < 512; ++k) a += style[b * 512 + k] * mw[c * 512 + k];
    s_sh[c] = a;
  }
  __syncthreads();
  float acc = 0.0f;
  for (int c = 0; c < 512; ++c) {
    float sc = s_sh[c];
    const float* wp = wt + ((size_t)co * 512 + c) * 9;
    for (int kh = 0; kh < 3; ++kh) {
      int hy = h + kh - 1;
      if (hy < 0 || hy >= 64) continue;
      for (int kw = 0; kw < 3; ++kw) {
        int wx = w + kw - 1;
        if (wx < 0 || wx >= 64) continue;
        acc += wp[kh * 3 + kw] * x[((size_t)(b * 512 + c) * 64 + hy) * 64 + wx] * sc;
      }
    }
  }
  out[((size_t)(b * 512 + co) * 64 + h) * 64 + w] = acc;
}

extern "C" void kernel_launch(void* const* d_in, const int* in_sizes, int n_in,
                              void* d_out, int out_size, void* d_ws, size_t ws_size,
                              hipStream_t stream) {
  const float* x      = (const float*)d_in[0];
  const float* style  = (const float*)d_in[1];
  const float* weight = (const float*)d_in[2];
  const float* mod_w  = (const float*)d_in[3];
  const float* mod_b  = (const float*)d_in[4];
  float* out = (float*)d_out;
  char* ws = (char*)d_ws;

  if (ws_size >= WS_NEEDED) {
    float* s  = (float*)(ws + WS_S);
    float* zb = (float*)(ws + WS_ZERO);
    char* xq  = ws + WS_XQ;
    char* wq  = ws + WS_WQ;
    k_style<<<1024, 256, 0, stream>>>(style, mod_w, mod_b, s, zb);
    k_xq<<<8192, 256, 0, stream>>>(x, s, xq);
    k_wq<<<dim3(9, 32, 4), 256, 0, stream>>>(weight, wq);
    k_conv<<<dim3(64, 4), 512, 115968, stream>>>(xq, wq, (const char*)zb, out);
  } else {
    k_naive<<<dim3(64, 512, 8), 64, 0, stream>>>(x, style, weight, mod_w, mod_b, out);
  }
}